// Round 1
// baseline (700.625 us; speedup 1.0000x reference)
//
#include <hip/hip_runtime.h>
#include <stdint.h>

// ---------------------------------------------------------------- constants
#define NB     8192     // batch
#define NF     256      // features
#define NHALF  128      // F/2
#define NHID   512      // hidden = 2F
#define NLAY   4        // coupling layers
#define NK     32768    // codebook size

typedef __attribute__((ext_vector_type(8))) short bf16x8;   // 8 bf16 = 4 VGPR
typedef __attribute__((ext_vector_type(4))) float f32x4;

static __device__ __forceinline__ unsigned short f2bf(float f) {
  union { float f; unsigned int u; } v; v.f = f;
  return (unsigned short)((v.u + 0x7FFFu + ((v.u >> 16) & 1u)) >> 16);  // RNE
}

// async global->LDS, 16B per lane; LDS dest = wave-uniform base + lane*16
static __device__ __forceinline__ void load_lds16(const void* g, void* l) {
  __builtin_amdgcn_global_load_lds(
      (const __attribute__((address_space(1))) unsigned int*)g,
      (__attribute__((address_space(3))) unsigned int*)l, 16, 0, 0);
}

// pack (score, idx) so u64 max == argmax with smallest-index tiebreak
static __device__ __forceinline__ unsigned long long packsi(float v, int idx) {
  unsigned int b = __float_as_uint(v);
  b = (b & 0x80000000u) ? ~b : (b | 0x80000000u);   // order-preserving map
  return ((unsigned long long)b << 32) | (unsigned int)(~(unsigned int)idx);
}

// ---------------------------------------------------------------- GEMM (B^T)
// C[m,n] = sum_k A[m,k]*Bt[n,k]; 128x128 tile, BK=64, 4 waves (2x2 of 64x64).
// MODE 0: out_bf16 = relu(C + bias0[n])          (flow GEMM1 -> h)
// MODE 1: out_f32  = C + (n<128 ? bias0 : bias1) (flow GEMM2 -> s|t)
template <int MODE>
__global__ __launch_bounds__(256)
void gemm_bt(const unsigned short* __restrict__ A, int lda,
             const unsigned short* __restrict__ Bt, int ldb, int K,
             const float* __restrict__ bias0, const float* __restrict__ bias1,
             unsigned short* __restrict__ outbf, float* __restrict__ outf, int ldo)
{
  __shared__ unsigned short As[128 * 64];
  __shared__ unsigned short Bs[128 * 64];
  const int tid = threadIdx.x;
  const int lane = tid & 63, wave = tid >> 6;
  const int wm = wave >> 1, wn = wave & 1;
  const int m0 = blockIdx.x * 128, n0 = blockIdx.y * 128;
  const int q = lane >> 4, c = lane & 15;

  const f32x4 z = {0.f, 0.f, 0.f, 0.f};
  f32x4 acc[4][4];
#pragma unroll
  for (int i = 0; i < 4; i++)
#pragma unroll
    for (int j = 0; j < 4; j++) acc[i][j] = z;

  for (int kt = 0; kt < K; kt += 64) {
#pragma unroll
    for (int i = 0; i < 4; i++) {
      const int cb = (wave * 4 + i) * 64;       // chunk base for this wave-inst
      const int chunk = cb + lane;
      const int m = chunk >> 3, ko = (chunk & 7) * 8;
      load_lds16(A  + (size_t)(m0 + m) * lda + kt + ko, As + cb * 8);
      load_lds16(Bt + (size_t)(n0 + m) * ldb + kt + ko, Bs + cb * 8);
    }
    __syncthreads();
#pragma unroll
    for (int ks = 0; ks < 2; ks++) {
      const int kb = ks * 32 + q * 8;
      bf16x8 af[4], bfm[4];
#pragma unroll
      for (int i = 0; i < 4; i++) {
        af[i]  = *(const bf16x8*)(As + (64 * wm + 16 * i + c) * 64 + kb);
        bfm[i] = *(const bf16x8*)(Bs + (64 * wn + 16 * i + c) * 64 + kb);
      }
#pragma unroll
      for (int i = 0; i < 4; i++)
#pragma unroll
        for (int j = 0; j < 4; j++)
          acc[i][j] = __builtin_amdgcn_mfma_f32_16x16x32_bf16(af[i], bfm[j], acc[i][j], 0, 0, 0);
    }
    __syncthreads();
  }

  // epilogue: D row=(lane>>4)*4+r, col=lane&15 (verified m89/m91 layout)
#pragma unroll
  for (int i = 0; i < 4; i++) {
    const int row = m0 + 64 * wm + 16 * i + q * 4;
#pragma unroll
    for (int j = 0; j < 4; j++) {
      const int col = n0 + 64 * wn + 16 * j + c;
#pragma unroll
      for (int r = 0; r < 4; r++) {
        float v = acc[i][j][r];
        if (MODE == 0) {
          v += bias0[col];
          v = v > 0.f ? v : 0.f;
          outbf[(size_t)(row + r) * ldo + col] = f2bf(v);
        } else {
          v += (col < NHALF) ? bias0[col] : bias1[col - NHALF];
          outf[(size_t)(row + r) * ldo + col] = v;
        }
      }
    }
  }
}

// ---------------------------------------------------------------- VQ argmax
// Per block: 128 rows x 4096 codes (32 tiles of 128), running per-row best in
// registers, block-merge in LDS, one atomicMax per row at the end.
__global__ __launch_bounds__(256)
void vq_argmax(const unsigned short* __restrict__ X,    // [NB][256] bf16
               const unsigned short* __restrict__ P,    // [NK][256] bf16
               const float* __restrict__ nbh,           // [NK] = 0.5*||p||^2
               unsigned long long* __restrict__ gbest)  // [NB] packed
{
  __shared__ unsigned short As[128 * 64];
  __shared__ unsigned short Bs[128 * 64];
  __shared__ unsigned long long red[128];
  const int tid = threadIdx.x;
  const int lane = tid & 63, wave = tid >> 6;
  const int wm = wave >> 1, wn = wave & 1;
  const int m0 = blockIdx.x * 128;
  const int q = lane >> 4, c = lane & 15;

  float bestv[16];
  int besti[16];
#pragma unroll
  for (int t = 0; t < 16; t++) { bestv[t] = -1e30f; besti[t] = 0; }

  for (int nt = 0; nt < 32; nt++) {
    const int n0 = blockIdx.y * 4096 + nt * 128;
    const f32x4 z = {0.f, 0.f, 0.f, 0.f};
    f32x4 acc[4][4];
#pragma unroll
    for (int i = 0; i < 4; i++)
#pragma unroll
      for (int j = 0; j < 4; j++) acc[i][j] = z;

    for (int kt = 0; kt < 256; kt += 64) {
#pragma unroll
      for (int i = 0; i < 4; i++) {
        const int cb = (wave * 4 + i) * 64;
        const int chunk = cb + lane;
        const int m = chunk >> 3, ko = (chunk & 7) * 8;
        load_lds16(X + (size_t)(m0 + m) * 256 + kt + ko, As + cb * 8);
        load_lds16(P + (size_t)(n0 + m) * 256 + kt + ko, Bs + cb * 8);
      }
      __syncthreads();
#pragma unroll
      for (int ks = 0; ks < 2; ks++) {
        const int kb = ks * 32 + q * 8;
        bf16x8 af[4], bfm[4];
#pragma unroll
        for (int i = 0; i < 4; i++) {
          af[i]  = *(const bf16x8*)(As + (64 * wm + 16 * i + c) * 64 + kb);
          bfm[i] = *(const bf16x8*)(Bs + (64 * wn + 16 * i + c) * 64 + kb);
        }
#pragma unroll
        for (int i = 0; i < 4; i++)
#pragma unroll
          for (int j = 0; j < 4; j++)
            acc[i][j] = __builtin_amdgcn_mfma_f32_16x16x32_bf16(af[i], bfm[j], acc[i][j], 0, 0, 0);
      }
      __syncthreads();
    }

    // score = x.p - 0.5||p||^2 ; per-row argmax over this 128-col tile
#pragma unroll
    for (int i = 0; i < 4; i++) {
#pragma unroll
      for (int r = 0; r < 4; r++) {
        float lv = -1e30f; int li = 0;
#pragma unroll
        for (int j = 0; j < 4; j++) {
          const int col = n0 + 64 * wn + 16 * j + c;
          const float sc = acc[i][j][r] - nbh[col];
          if (sc > lv || (sc == lv && col < li)) { lv = sc; li = col; }
        }
#pragma unroll
        for (int mk = 8; mk >= 1; mk >>= 1) {   // reduce across 16-lane group
          const float ov = __shfl_xor(lv, mk);
          const int oi = __shfl_xor(li, mk);
          if (ov > lv || (ov == lv && oi < li)) { lv = ov; li = oi; }
        }
        const int t = i * 4 + r;
        if (lv > bestv[t] || (lv == bestv[t] && li < besti[t])) { bestv[t] = lv; besti[t] = li; }
      }
    }
  }

  // merge the two column-waves sharing each row, then global atomicMax
  if (wn == 0 && c == 0) {
#pragma unroll
    for (int i = 0; i < 4; i++)
#pragma unroll
      for (int r = 0; r < 4; r++)
        red[64 * wm + 16 * i + q * 4 + r] = packsi(bestv[i * 4 + r], besti[i * 4 + r]);
  }
  __syncthreads();
  if (wn == 1 && c == 0) {
#pragma unroll
    for (int i = 0; i < 4; i++)
#pragma unroll
      for (int r = 0; r < 4; r++) {
        const int lr = 64 * wm + 16 * i + q * 4 + r;
        unsigned long long mine = packsi(bestv[i * 4 + r], besti[i * 4 + r]);
        const unsigned long long o = red[lr];
        if (o > mine) mine = o;
        atomicMax(&gbest[m0 + lr], mine);
      }
  }
}

// ---------------------------------------------------------------- prep kernels
__global__ void prep_weights(const float* __restrict__ W1,
                             const float* __restrict__ Ws,
                             const float* __restrict__ Wt,
                             unsigned short* __restrict__ W1T,   // [L][512][128]
                             unsigned short* __restrict__ W2T)   // [L][256][512]
{
  const int idx = blockIdx.x * 256 + threadIdx.x;
  if (idx < NLAY * NHID * NHALF) {            // 262144
    const int l = idx >> 16;
    const int n = (idx >> 7) & 511;
    const int k = idx & 127;
    W1T[idx] = f2bf(W1[((size_t)l * NHALF + k) * NHID + n]);
  } else {
    const int j = idx - NLAY * NHID * NHALF;  // 524288
    if (j < NLAY * NF * NHID) {
      const int l = j >> 17;
      const int n = (j >> 9) & 255;
      const int k = j & 511;
      const float v = (n < NHALF) ? Ws[((size_t)l * NHID + k) * NHALF + n]
                                  : Wt[((size_t)l * NHID + k) * NHALF + (n - NHALF)];
      W2T[j] = f2bf(v);
    }
  }
}

__global__ void prep_prior(const float* __restrict__ prior,
                           unsigned short* __restrict__ pbf,
                           float* __restrict__ nbh)
{
  const int k = blockIdx.x * 4 + (threadIdx.x >> 6);   // one wave per code
  const int lane = threadIdx.x & 63;
  const float4 v = *(const float4*)(prior + (size_t)k * NF + lane * 4);
  ushort4 o;
  o.x = f2bf(v.x); o.y = f2bf(v.y); o.z = f2bf(v.z); o.w = f2bf(v.w);
  *(ushort4*)(pbf + (size_t)k * NF + lane * 4) = o;
  float s = v.x * v.x + v.y * v.y + v.z * v.z + v.w * v.w;
#pragma unroll
  for (int mk = 32; mk >= 1; mk >>= 1) s += __shfl_xor(s, mk);
  if (lane == 0) nbh[k] = 0.5f * s;
}

__global__ void prep_x0(const float* __restrict__ in,
                        unsigned short* __restrict__ xabf,   // [NB][128] bf16
                        float* __restrict__ jac,
                        unsigned long long* __restrict__ gbest,
                        float* __restrict__ accum)
{
  const int idx = blockIdx.x * 256 + threadIdx.x;
  if (idx < NB * NHALF) {
    const int b = idx >> 7, j = idx & 127;
    xabf[idx] = f2bf(in[((size_t)b << 8) + j]);
  }
  if (idx < NB) { jac[idx] = 0.f; gbest[idx] = 0ull; }
  if (idx < 2) accum[idx] = 0.f;
}

// ---------------------------------------------------------------- coupling epilogue
// yb = xb*exp(s)+t ; x_next = [yb, xa] ; jac += sum(s). One wave per row.
__global__ void couple_ep(const float* __restrict__ st,    // [NB][256] s|t
                          const float* __restrict__ xcur,  // [NB][256]
                          float* __restrict__ xnext,       // [NB][256]
                          unsigned short* __restrict__ xabf,   // next-layer A (bf16)
                          unsigned short* __restrict__ xfbf,   // last layer: full x bf16
                          float* __restrict__ jac, int is_last)
{
  const int b = blockIdx.x * 4 + (threadIdx.x >> 6);
  const int lane = threadIdx.x & 63;
  const float* srow = st + (size_t)b * NF;
  const float* xrow = xcur + (size_t)b * NF;
  float jsum = 0.f;
#pragma unroll
  for (int u = 0; u < 2; u++) {
    const int j = lane * 2 + u;                // 0..127
    float s = srow[j];
    if (!is_last) s = tanhf(s);
    const float t = srow[NHALF + j];
    const float xa = xrow[j], xb = xrow[NHALF + j];
    const float yb = xb * __expf(s) + t;
    jsum += s;
    xnext[(size_t)b * NF + j] = yb;
    xnext[(size_t)b * NF + NHALF + j] = xa;
    if (!is_last) {
      xabf[(size_t)b * NHALF + j] = f2bf(yb);
    } else {
      xfbf[(size_t)b * NF + j] = f2bf(yb);
      xfbf[(size_t)b * NF + NHALF + j] = f2bf(xa);
    }
  }
#pragma unroll
  for (int mk = 32; mk >= 1; mk >>= 1) jsum += __shfl_xor(jsum, mk);
  if (lane == 0) jac[b] += jsum;
}

// ---------------------------------------------------------------- VQ finalize
// Exact fp32 ||x - prior[best]||^2 + jac, block-reduced, 2 atomics per block.
__global__ void vq_finalize(const float* __restrict__ X,      // d_out x, fp32
                            const float* __restrict__ prior,
                            const unsigned long long* __restrict__ gbest,
                            const float* __restrict__ jac,
                            float* __restrict__ accum)        // [0]=dist,[1]=jac
{
  const int wave = threadIdx.x >> 6, lane = threadIdx.x & 63;
  const int gw = blockIdx.x * 4 + wave;        // 1024 waves, 8 rows each
  float accd = 0.f, accj = 0.f;
  for (int r = 0; r < 8; r++) {
    const int row = gw * 8 + r;
    const unsigned int idx = ~(unsigned int)(gbest[row]);   // low 32 bits = ~idx
    const float* x = X + (size_t)row * NF;
    const float* p = prior + (size_t)idx * NF;
#pragma unroll
    for (int u = 0; u < 4; u++) {
      const int d = lane + u * 64;
      const float df = x[d] - p[d];
      accd += df * df;
    }
    if (lane == 0) accj += jac[row];
  }
#pragma unroll
  for (int mk = 32; mk >= 1; mk >>= 1) {
    accd += __shfl_xor(accd, mk);
    accj += __shfl_xor(accj, mk);
  }
  __shared__ float sd[4], sj[4];
  if (lane == 0) { sd[wave] = accd; sj[wave] = accj; }
  __syncthreads();
  if (threadIdx.x == 0) {
    atomicAdd(&accum[0], sd[0] + sd[1] + sd[2] + sd[3]);
    atomicAdd(&accum[1], sj[0] + sj[1] + sj[2] + sj[3]);
  }
}

__global__ void finalize_loss(const float* __restrict__ acc, float* __restrict__ loss) {
  if (threadIdx.x == 0 && blockIdx.x == 0)
    loss[0] = 1.25f * (0.5f * acc[0] / (float)NB) - acc[1] / (float)NB;
}

// ---------------------------------------------------------------- launch
extern "C" void kernel_launch(void* const* d_in, const int* in_sizes, int n_in,
                              void* d_out, int out_size, void* d_ws, size_t ws_size,
                              hipStream_t stream)
{
  (void)in_sizes; (void)n_in; (void)out_size; (void)ws_size;
  const float* inputs = (const float*)d_in[0];
  const float* W1 = (const float*)d_in[1];
  const float* b1 = (const float*)d_in[2];
  const float* Ws = (const float*)d_in[3];
  const float* bs = (const float*)d_in[4];
  const float* Wt = (const float*)d_in[5];
  const float* bt = (const float*)d_in[6];
  const float* prior = (const float*)d_in[7];

  char* p = (char*)d_ws;
  auto alloc = [&](size_t bytes) { char* r = p; p += (bytes + 255) & ~(size_t)255; return r; };
  unsigned short* W1T  = (unsigned short*)alloc((size_t)NLAY * NHID * NHALF * 2);
  unsigned short* W2T  = (unsigned short*)alloc((size_t)NLAY * NF * NHID * 2);
  unsigned short* PBF  = (unsigned short*)alloc((size_t)NK * NF * 2);
  float* NBH           = (float*)alloc((size_t)NK * 4);
  unsigned short* XABF = (unsigned short*)alloc((size_t)NB * NHALF * 2);
  unsigned short* HBF  = (unsigned short*)alloc((size_t)NB * NHID * 2);
  float* ST            = (float*)alloc((size_t)NB * NF * 4);
  float* X0            = (float*)alloc((size_t)NB * NF * 4);
  float* X1            = (float*)alloc((size_t)NB * NF * 4);
  unsigned short* XFBF = (unsigned short*)alloc((size_t)NB * NF * 2);
  float* JAC           = (float*)alloc((size_t)NB * 4);
  unsigned long long* GBEST = (unsigned long long*)alloc((size_t)NB * 8);
  float* ACC           = (float*)alloc(256);

  float* xout = (float*)d_out;                 // [NB][NF]
  float* loss = xout + (size_t)NB * NF;        // scalar

  prep_weights<<<dim3((NLAY * NHID * NHALF + NLAY * NF * NHID) / 256), 256, 0, stream>>>(
      W1, Ws, Wt, W1T, W2T);
  prep_prior<<<dim3(NK / 4), 256, 0, stream>>>(prior, PBF, NBH);
  prep_x0<<<dim3(NB * NHALF / 256), 256, 0, stream>>>(inputs, XABF, JAC, GBEST, ACC);

  const float* xcur = inputs;
  for (int l = 0; l < NLAY; l++) {
    gemm_bt<0><<<dim3(NB / 128, NHID / 128), 256, 0, stream>>>(
        XABF, NHALF, W1T + (size_t)l * NHID * NHALF, NHALF, NHALF,
        b1 + l * NHID, nullptr, HBF, nullptr, NHID);
    gemm_bt<1><<<dim3(NB / 128, NF / 128), 256, 0, stream>>>(
        HBF, NHID, W2T + (size_t)l * NF * NHID, NHID, NHID,
        bs + l * NHALF, bt + l * NHALF, nullptr, ST, NF);
    const int last = (l == NLAY - 1);
    float* xo = last ? xout : ((l & 1) ? X1 : X0);
    couple_ep<<<dim3(NB / 4), 256, 0, stream>>>(ST, xcur, xo, XABF, XFBF, JAC, last);
    xcur = xo;
  }

  vq_argmax<<<dim3(NB / 128, 8), 256, 0, stream>>>(XFBF, PBF, NBH, GBEST);
  vq_finalize<<<dim3(256), 256, 0, stream>>>(xout, prior, GBEST, JAC, ACC);
  finalize_loss<<<1, 1, 0, stream>>>(ACC, loss);
}

// Round 2
// 542.797 us; speedup vs baseline: 1.2908x; 1.2908x over previous
//
#include <hip/hip_runtime.h>
#include <stdint.h>

// ---------------------------------------------------------------- constants
#define NB     8192     // batch
#define NF     256      // features
#define NHALF  128      // F/2
#define NHID   512      // hidden = 2F
#define NLAY   4        // coupling layers
#define NK     32768    // codebook size

typedef __attribute__((ext_vector_type(8))) short bf16x8;   // 8 bf16 = 4 VGPR
typedef __attribute__((ext_vector_type(4))) float f32x4;

static __device__ __forceinline__ unsigned short f2bf(float f) {
  union { float f; unsigned int u; } v; v.f = f;
  return (unsigned short)((v.u + 0x7FFFu + ((v.u >> 16) & 1u)) >> 16);  // RNE
}

// async global->LDS, 16B per lane; LDS dest = wave-uniform base + lane*16
static __device__ __forceinline__ void load_lds16(const void* g, void* l) {
  __builtin_amdgcn_global_load_lds(
      (const __attribute__((address_space(1))) unsigned int*)g,
      (__attribute__((address_space(3))) unsigned int*)l, 16, 0, 0);
}

// pack (score, idx) so u64 max == argmax with smallest-index tiebreak
static __device__ __forceinline__ unsigned long long packsi(float v, int idx) {
  unsigned int b = __float_as_uint(v);
  b = (b & 0x80000000u) ? ~b : (b | 0x80000000u);   // order-preserving map
  return ((unsigned long long)b << 32) | (unsigned int)(~(unsigned int)idx);
}

// ---------------------------------------------------------------- GEMM (B^T)
// C[m,n] = sum_k A[m,k]*Bt[n,k]; 128x128 tile, BK=64, 4 waves (2x2 of 64x64).
// LDS layout XOR-swizzled: row m's 16B-chunk c' holds global chunk c'^(m&7),
// so ds_read_b128 lanes spread over all 8 bank groups (2-way = free).
// MODE 0: out_bf16 = relu(C + bias0[n])          (flow GEMM1 -> h)
// MODE 1: out_f32  = C + (n<128 ? bias0 : bias1) (flow GEMM2 -> s|t)
template <int MODE>
__global__ __launch_bounds__(256, 4)
void gemm_bt(const unsigned short* __restrict__ A, int lda,
             const unsigned short* __restrict__ Bt, int ldb, int K,
             const float* __restrict__ bias0, const float* __restrict__ bias1,
             unsigned short* __restrict__ outbf, float* __restrict__ outf, int ldo)
{
  __shared__ unsigned short As[128 * 64];
  __shared__ unsigned short Bs[128 * 64];
  const int tid = threadIdx.x;
  const int lane = tid & 63, wave = tid >> 6;
  const int wm = wave >> 1, wn = wave & 1;
  const int m0 = blockIdx.x * 128, n0 = blockIdx.y * 128;
  const int q = lane >> 4, c = lane & 15;

  const f32x4 z = {0.f, 0.f, 0.f, 0.f};
  f32x4 acc[4][4];
#pragma unroll
  for (int i = 0; i < 4; i++)
#pragma unroll
    for (int j = 0; j < 4; j++) acc[i][j] = z;

  for (int kt = 0; kt < K; kt += 64) {
#pragma unroll
    for (int i = 0; i < 4; i++) {
      const int cb = (wave * 4 + i) * 64;       // chunk base for this wave-inst
      const int s = cb + lane;                  // LDS slot index
      const int m = s >> 3;
      const int ko = ((s & 7) ^ (m & 7)) * 8;   // swizzled source chunk
      load_lds16(A  + (size_t)(m0 + m) * lda + kt + ko, As + cb * 8);
      load_lds16(Bt + (size_t)(n0 + m) * ldb + kt + ko, Bs + cb * 8);
    }
    __syncthreads();
#pragma unroll
    for (int ks = 0; ks < 2; ks++) {
#pragma unroll
      for (int i = 0; i < 4; i++) {
        const int ra = 64 * wm + 16 * i + c;
        const int rb = 64 * wn + 16 * i + c;
        const int cca = ((ks * 4 + q) ^ (ra & 7)) * 8;
        const int ccb = ((ks * 4 + q) ^ (rb & 7)) * 8;
        bf16x8 af  = *(const bf16x8*)(As + ra * 64 + cca);
        bf16x8 bfm = *(const bf16x8*)(Bs + rb * 64 + ccb);
        // NOTE: need af[i] x bfm[j] cross products; reload per (i,j) would be
        // wasteful -> gather all 4 of each first.
        (void)af; (void)bfm;
      }
      bf16x8 af[4], bfm[4];
#pragma unroll
      for (int i = 0; i < 4; i++) {
        const int ra = 64 * wm + 16 * i + c;
        const int rb = 64 * wn + 16 * i + c;
        af[i]  = *(const bf16x8*)(As + ra * 64 + ((ks * 4 + q) ^ (ra & 7)) * 8);
        bfm[i] = *(const bf16x8*)(Bs + rb * 64 + ((ks * 4 + q) ^ (rb & 7)) * 8);
      }
#pragma unroll
      for (int i = 0; i < 4; i++)
#pragma unroll
        for (int j = 0; j < 4; j++)
          acc[i][j] = __builtin_amdgcn_mfma_f32_16x16x32_bf16(af[i], bfm[j], acc[i][j], 0, 0, 0);
    }
    __syncthreads();
  }

  // epilogue: D row=(lane>>4)*4+r, col=lane&15 (verified m89/m91 layout)
#pragma unroll
  for (int i = 0; i < 4; i++) {
    const int row = m0 + 64 * wm + 16 * i + q * 4;
#pragma unroll
    for (int j = 0; j < 4; j++) {
      const int col = n0 + 64 * wn + 16 * j + c;
#pragma unroll
      for (int r = 0; r < 4; r++) {
        float v = acc[i][j][r];
        if (MODE == 0) {
          v += bias0[col];
          v = v > 0.f ? v : 0.f;
          outbf[(size_t)(row + r) * ldo + col] = f2bf(v);
        } else {
          v += (col < NHALF) ? bias0[col] : bias1[col - NHALF];
          outf[(size_t)(row + r) * ldo + col] = v;
        }
      }
    }
  }
}

// ---------------------------------------------------------------- VQ argmax
// Grid (NB/128, 16): per block 128 rows x 2048 codes (16 tiles of 128).
// Lane-local running best across tiles (no per-tile shuffles), one 4-level
// shuffle reduce + LDS merge + atomicMax per block at the end.
__global__ __launch_bounds__(256, 4)
void vq_argmax(const unsigned short* __restrict__ X,    // [NB][256] bf16
               const unsigned short* __restrict__ P,    // [NK][256] bf16
               const float* __restrict__ nbh,           // [NK] = 0.5*||p||^2
               unsigned long long* __restrict__ gbest)  // [NB] packed
{
  __shared__ unsigned short As[128 * 64];
  __shared__ unsigned short Bs[128 * 64];
  __shared__ unsigned long long red[128];
  const int tid = threadIdx.x;
  const int lane = tid & 63, wave = tid >> 6;
  const int wm = wave >> 1, wn = wave & 1;
  const int m0 = blockIdx.x * 128;
  const int q = lane >> 4, c = lane & 15;

  float bestv[16];
  int besti[16];
#pragma unroll
  for (int t = 0; t < 16; t++) { bestv[t] = -1e30f; besti[t] = 0; }

  for (int nt = 0; nt < 16; nt++) {
    const int n0 = blockIdx.y * 2048 + nt * 128;
    const f32x4 z = {0.f, 0.f, 0.f, 0.f};
    f32x4 acc[4][4];
#pragma unroll
    for (int i = 0; i < 4; i++)
#pragma unroll
      for (int j = 0; j < 4; j++) acc[i][j] = z;

    for (int kt = 0; kt < 256; kt += 64) {
#pragma unroll
      for (int i = 0; i < 4; i++) {
        const int cb = (wave * 4 + i) * 64;
        const int s = cb + lane;
        const int m = s >> 3;
        const int ko = ((s & 7) ^ (m & 7)) * 8;
        load_lds16(X + (size_t)(m0 + m) * 256 + kt + ko, As + cb * 8);
        load_lds16(P + (size_t)(n0 + m) * 256 + kt + ko, Bs + cb * 8);
      }
      __syncthreads();
#pragma unroll
      for (int ks = 0; ks < 2; ks++) {
        bf16x8 af[4], bfm[4];
#pragma unroll
        for (int i = 0; i < 4; i++) {
          const int ra = 64 * wm + 16 * i + c;
          const int rb = 64 * wn + 16 * i + c;
          af[i]  = *(const bf16x8*)(As + ra * 64 + ((ks * 4 + q) ^ (ra & 7)) * 8);
          bfm[i] = *(const bf16x8*)(Bs + rb * 64 + ((ks * 4 + q) ^ (rb & 7)) * 8);
        }
#pragma unroll
        for (int i = 0; i < 4; i++)
#pragma unroll
          for (int j = 0; j < 4; j++)
            acc[i][j] = __builtin_amdgcn_mfma_f32_16x16x32_bf16(af[i], bfm[j], acc[i][j], 0, 0, 0);
      }
      __syncthreads();
    }

    // score = x.p - 0.5||p||^2 ; lane-local running argmax (ascending col
    // within lane + strict > keeps the first/lowest index on ties)
#pragma unroll
    for (int j = 0; j < 4; j++) {
      const int col = n0 + 64 * wn + 16 * j + c;
      const float nb = nbh[col];
#pragma unroll
      for (int i = 0; i < 4; i++)
#pragma unroll
        for (int r = 0; r < 4; r++) {
          const float sc = acc[i][j][r] - nb;
          const int t = i * 4 + r;
          if (sc > bestv[t]) { bestv[t] = sc; besti[t] = col; }
        }
    }
  }

  // once per block: reduce across the 16 c-lanes (lane bits 0..3) per t
#pragma unroll
  for (int t = 0; t < 16; t++) {
    float lv = bestv[t]; int li = besti[t];
#pragma unroll
    for (int mk = 8; mk >= 1; mk >>= 1) {
      const float ov = __shfl_xor(lv, mk);
      const int oi = __shfl_xor(li, mk);
      if (ov > lv || (ov == lv && oi < li)) { lv = ov; li = oi; }
    }
    bestv[t] = lv; besti[t] = li;
  }

  // merge the two column-waves sharing each row, then global atomicMax
  if (wn == 0 && c == 0) {
#pragma unroll
    for (int i = 0; i < 4; i++)
#pragma unroll
      for (int r = 0; r < 4; r++)
        red[64 * wm + 16 * i + q * 4 + r] = packsi(bestv[i * 4 + r], besti[i * 4 + r]);
  }
  __syncthreads();
  if (wn == 1 && c == 0) {
#pragma unroll
    for (int i = 0; i < 4; i++)
#pragma unroll
      for (int r = 0; r < 4; r++) {
        const int lr = 64 * wm + 16 * i + q * 4 + r;
        unsigned long long mine = packsi(bestv[i * 4 + r], besti[i * 4 + r]);
        const unsigned long long o = red[lr];
        if (o > mine) mine = o;
        atomicMax(&gbest[m0 + lr], mine);
      }
  }
}

// ---------------------------------------------------------------- prep kernels
__global__ void prep_weights(const float* __restrict__ W1,
                             const float* __restrict__ Ws,
                             const float* __restrict__ Wt,
                             unsigned short* __restrict__ W1T,   // [L][512][128]
                             unsigned short* __restrict__ W2T)   // [L][256][512]
{
  const int idx = blockIdx.x * 256 + threadIdx.x;
  if (idx < NLAY * NHID * NHALF) {            // 262144
    const int l = idx >> 16;
    const int n = (idx >> 7) & 511;
    const int k = idx & 127;
    W1T[idx] = f2bf(W1[((size_t)l * NHALF + k) * NHID + n]);
  } else {
    const int j = idx - NLAY * NHID * NHALF;  // 524288
    if (j < NLAY * NF * NHID) {
      const int l = j >> 17;
      const int n = (j >> 9) & 255;
      const int k = j & 511;
      const float v = (n < NHALF) ? Ws[((size_t)l * NHID + k) * NHALF + n]
                                  : Wt[((size_t)l * NHID + k) * NHALF + (n - NHALF)];
      W2T[j] = f2bf(v);
    }
  }
}

__global__ void prep_prior(const float* __restrict__ prior,
                           unsigned short* __restrict__ pbf,
                           float* __restrict__ nbh)
{
  const int k = blockIdx.x * 4 + (threadIdx.x >> 6);   // one wave per code
  const int lane = threadIdx.x & 63;
  const float4 v = *(const float4*)(prior + (size_t)k * NF + lane * 4);
  ushort4 o;
  o.x = f2bf(v.x); o.y = f2bf(v.y); o.z = f2bf(v.z); o.w = f2bf(v.w);
  *(ushort4*)(pbf + (size_t)k * NF + lane * 4) = o;
  float s = v.x * v.x + v.y * v.y + v.z * v.z + v.w * v.w;
#pragma unroll
  for (int mk = 32; mk >= 1; mk >>= 1) s += __shfl_xor(s, mk);
  if (lane == 0) nbh[k] = 0.5f * s;
}

__global__ void prep_x0(const float* __restrict__ in,
                        unsigned short* __restrict__ xabf,   // [NB][128] bf16
                        float* __restrict__ jac,
                        unsigned long long* __restrict__ gbest,
                        float* __restrict__ accum)
{
  const int idx = blockIdx.x * 256 + threadIdx.x;
  if (idx < NB * NHALF) {
    const int b = idx >> 7, j = idx & 127;
    xabf[idx] = f2bf(in[((size_t)b << 8) + j]);
  }
  if (idx < NB) { jac[idx] = 0.f; gbest[idx] = 0ull; }
  if (idx < 2) accum[idx] = 0.f;
}

// ---------------------------------------------------------------- coupling epilogue
// yb = xb*exp(s)+t ; x_next = [yb, xa] ; jac += sum(s). One wave per row.
__global__ void couple_ep(const float* __restrict__ st,    // [NB][256] s|t
                          const float* __restrict__ xcur,  // [NB][256]
                          float* __restrict__ xnext,       // [NB][256]
                          unsigned short* __restrict__ xabf,   // next-layer A (bf16)
                          unsigned short* __restrict__ xfbf,   // last layer: full x bf16
                          float* __restrict__ jac, int is_last)
{
  const int b = blockIdx.x * 4 + (threadIdx.x >> 6);
  const int lane = threadIdx.x & 63;
  const float* srow = st + (size_t)b * NF;
  const float* xrow = xcur + (size_t)b * NF;
  float jsum = 0.f;
#pragma unroll
  for (int u = 0; u < 2; u++) {
    const int j = lane * 2 + u;                // 0..127
    float s = srow[j];
    if (!is_last) s = tanhf(s);
    const float t = srow[NHALF + j];
    const float xa = xrow[j], xb = xrow[NHALF + j];
    const float yb = xb * __expf(s) + t;
    jsum += s;
    xnext[(size_t)b * NF + j] = yb;
    xnext[(size_t)b * NF + NHALF + j] = xa;
    if (!is_last) {
      xabf[(size_t)b * NHALF + j] = f2bf(yb);
    } else {
      xfbf[(size_t)b * NF + j] = f2bf(yb);
      xfbf[(size_t)b * NF + NHALF + j] = f2bf(xa);
    }
  }
#pragma unroll
  for (int mk = 32; mk >= 1; mk >>= 1) jsum += __shfl_xor(jsum, mk);
  if (lane == 0) jac[b] += jsum;
}

// ---------------------------------------------------------------- VQ finalize
// Exact fp32 ||x - prior[best]||^2 + jac, block-reduced, 2 atomics per block.
__global__ void vq_finalize(const float* __restrict__ X,      // d_out x, fp32
                            const float* __restrict__ prior,
                            const unsigned long long* __restrict__ gbest,
                            const float* __restrict__ jac,
                            float* __restrict__ accum)        // [0]=dist,[1]=jac
{
  const int wave = threadIdx.x >> 6, lane = threadIdx.x & 63;
  const int gw = blockIdx.x * 4 + wave;        // 1024 waves, 8 rows each
  float accd = 0.f, accj = 0.f;
  for (int r = 0; r < 8; r++) {
    const int row = gw * 8 + r;
    const unsigned int idx = ~(unsigned int)(gbest[row]);   // low 32 bits = ~idx
    const float* x = X + (size_t)row * NF;
    const float* p = prior + (size_t)idx * NF;
#pragma unroll
    for (int u = 0; u < 4; u++) {
      const int d = lane + u * 64;
      const float df = x[d] - p[d];
      accd += df * df;
    }
    if (lane == 0) accj += jac[row];
  }
#pragma unroll
  for (int mk = 32; mk >= 1; mk >>= 1) {
    accd += __shfl_xor(accd, mk);
    accj += __shfl_xor(accj, mk);
  }
  __shared__ float sd[4], sj[4];
  if (lane == 0) { sd[wave] = accd; sj[wave] = accj; }
  __syncthreads();
  if (threadIdx.x == 0) {
    atomicAdd(&accum[0], sd[0] + sd[1] + sd[2] + sd[3]);
    atomicAdd(&accum[1], sj[0] + sj[1] + sj[2] + sj[3]);
  }
}

__global__ void finalize_loss(const float* __restrict__ acc, float* __restrict__ loss) {
  if (threadIdx.x == 0 && blockIdx.x == 0)
    loss[0] = 1.25f * (0.5f * acc[0] / (float)NB) - acc[1] / (float)NB;
}

// ---------------------------------------------------------------- launch
extern "C" void kernel_launch(void* const* d_in, const int* in_sizes, int n_in,
                              void* d_out, int out_size, void* d_ws, size_t ws_size,
                              hipStream_t stream)
{
  (void)in_sizes; (void)n_in; (void)out_size; (void)ws_size;
  const float* inputs = (const float*)d_in[0];
  const float* W1 = (const float*)d_in[1];
  const float* b1 = (const float*)d_in[2];
  const float* Ws = (const float*)d_in[3];
  const float* bs = (const float*)d_in[4];
  const float* Wt = (const float*)d_in[5];
  const float* bt = (const float*)d_in[6];
  const float* prior = (const float*)d_in[7];

  char* p = (char*)d_ws;
  auto alloc = [&](size_t bytes) { char* r = p; p += (bytes + 255) & ~(size_t)255; return r; };
  unsigned short* W1T  = (unsigned short*)alloc((size_t)NLAY * NHID * NHALF * 2);
  unsigned short* W2T  = (unsigned short*)alloc((size_t)NLAY * NF * NHID * 2);
  unsigned short* PBF  = (unsigned short*)alloc((size_t)NK * NF * 2);
  float* NBH           = (float*)alloc((size_t)NK * 4);
  unsigned short* XABF = (unsigned short*)alloc((size_t)NB * NHALF * 2);
  unsigned short* HBF  = (unsigned short*)alloc((size_t)NB * NHID * 2);
  float* ST            = (float*)alloc((size_t)NB * NF * 4);
  float* X0            = (float*)alloc((size_t)NB * NF * 4);
  float* X1            = (float*)alloc((size_t)NB * NF * 4);
  unsigned short* XFBF = (unsigned short*)alloc((size_t)NB * NF * 2);
  float* JAC           = (float*)alloc((size_t)NB * 4);
  unsigned long long* GBEST = (unsigned long long*)alloc((size_t)NB * 8);
  float* ACC           = (float*)alloc(256);

  float* xout = (float*)d_out;                 // [NB][NF]
  float* loss = xout + (size_t)NB * NF;        // scalar

  prep_weights<<<dim3((NLAY * NHID * NHALF + NLAY * NF * NHID) / 256), 256, 0, stream>>>(
      W1, Ws, Wt, W1T, W2T);
  prep_prior<<<dim3(NK / 4), 256, 0, stream>>>(prior, PBF, NBH);
  prep_x0<<<dim3(NB * NHALF / 256), 256, 0, stream>>>(inputs, XABF, JAC, GBEST, ACC);

  const float* xcur = inputs;
  for (int l = 0; l < NLAY; l++) {
    gemm_bt<0><<<dim3(NB / 128, NHID / 128), 256, 0, stream>>>(
        XABF, NHALF, W1T + (size_t)l * NHID * NHALF, NHALF, NHALF,
        b1 + l * NHID, nullptr, HBF, nullptr, NHID);
    gemm_bt<1><<<dim3(NB / 128, NF / 128), 256, 0, stream>>>(
        HBF, NHID, W2T + (size_t)l * NF * NHID, NHID, NHID,
        bs + l * NHALF, bt + l * NHALF, nullptr, ST, NF);
    const int last = (l == NLAY - 1);
    float* xo = last ? xout : ((l & 1) ? X1 : X0);
    couple_ep<<<dim3(NB / 4), 256, 0, stream>>>(ST, xcur, xo, XABF, XFBF, JAC, last);
    xcur = xo;
  }

  vq_argmax<<<dim3(NB / 128, 16), 256, 0, stream>>>(XFBF, PBF, NBH, GBEST);
  vq_finalize<<<dim3(256), 256, 0, stream>>>(xout, prior, GBEST, JAC, ACC);
  finalize_loss<<<1, 1, 0, stream>>>(ACC, loss);
}

// Round 3
// 464.841 us; speedup vs baseline: 1.5072x; 1.1677x over previous
//
#include <hip/hip_runtime.h>
#include <stdint.h>

// ---------------------------------------------------------------- constants
#define NB     8192     // batch
#define NF     256      // features
#define NHALF  128      // F/2
#define NHID   512      // hidden = 2F
#define NLAY   4        // coupling layers
#define NK     32768    // codebook size

typedef __attribute__((ext_vector_type(8))) short bf16x8;   // 8 bf16 = 4 VGPR
typedef __attribute__((ext_vector_type(4))) float f32x4;

static __device__ __forceinline__ unsigned short f2bf(float f) {
  union { float f; unsigned int u; } v; v.f = f;
  return (unsigned short)((v.u + 0x7FFFu + ((v.u >> 16) & 1u)) >> 16);  // RNE
}

// async global->LDS, 16B per lane; LDS dest = wave-uniform base + lane*16
static __device__ __forceinline__ void load_lds16(const void* g, void* l) {
  __builtin_amdgcn_global_load_lds(
      (const __attribute__((address_space(1))) unsigned int*)g,
      (__attribute__((address_space(3))) unsigned int*)l, 16, 0, 0);
}

// pack (score, idx) so u64 max == argmax with smallest-index tiebreak
static __device__ __forceinline__ unsigned long long packsi(float v, int idx) {
  unsigned int b = __float_as_uint(v);
  b = (b & 0x80000000u) ? ~b : (b | 0x80000000u);   // order-preserving map
  return ((unsigned long long)b << 32) | (unsigned int)(~(unsigned int)idx);
}

static __device__ __forceinline__ float fast_tanh(float x) {
  const float xc = fminf(fmaxf(x, -15.f), 15.f);
  const float e2 = __expf(2.f * xc);
  return 1.f - 2.f / (e2 + 1.f);
}

// ---------------------------------------------------------------- GEMM1 (B^T)
// C[m,n] = sum_k A[m,k]*Bt[n,k]; 128x128 tile, BK=64, 4 waves (2x2 of 64x64).
// LDS XOR-swizzled (slot chunk c' of row m holds global chunk c'^(m&7)).
// out_bf16 = relu(C + bias0[n])   (flow GEMM1 -> h)
__global__ __launch_bounds__(256, 4)
void gemm1(const unsigned short* __restrict__ A, int lda,
           const unsigned short* __restrict__ Bt, int ldb, int K,
           const float* __restrict__ bias0,
           unsigned short* __restrict__ outbf, int ldo)
{
  __shared__ unsigned short As[128 * 64];
  __shared__ unsigned short Bs[128 * 64];
  const int tid = threadIdx.x;
  const int lane = tid & 63, wave = tid >> 6;
  const int wm = wave >> 1, wn = wave & 1;
  const int m0 = blockIdx.x * 128, n0 = blockIdx.y * 128;
  const int q = lane >> 4, c = lane & 15;

  const f32x4 z = {0.f, 0.f, 0.f, 0.f};
  f32x4 acc[4][4];
#pragma unroll
  for (int i = 0; i < 4; i++)
#pragma unroll
    for (int j = 0; j < 4; j++) acc[i][j] = z;

  for (int kt = 0; kt < K; kt += 64) {
#pragma unroll
    for (int i = 0; i < 4; i++) {
      const int cb = (wave * 4 + i) * 64;       // uniform chunk base
      const int s = cb + lane;
      const int m = s >> 3;
      const int ko = ((s & 7) ^ (m & 7)) * 8;
      load_lds16(A  + (size_t)(m0 + m) * lda + kt + ko, As + cb * 8);
      load_lds16(Bt + (size_t)(n0 + m) * ldb + kt + ko, Bs + cb * 8);
    }
    __syncthreads();
#pragma unroll
    for (int ks = 0; ks < 2; ks++) {
      bf16x8 af[4], bfm[4];
#pragma unroll
      for (int i = 0; i < 4; i++) {
        const int ra = 64 * wm + 16 * i + c;
        const int rb = 64 * wn + 16 * i + c;
        af[i]  = *(const bf16x8*)(As + ra * 64 + ((ks * 4 + q) ^ (ra & 7)) * 8);
        bfm[i] = *(const bf16x8*)(Bs + rb * 64 + ((ks * 4 + q) ^ (rb & 7)) * 8);
      }
#pragma unroll
      for (int i = 0; i < 4; i++)
#pragma unroll
        for (int j = 0; j < 4; j++)
          acc[i][j] = __builtin_amdgcn_mfma_f32_16x16x32_bf16(af[i], bfm[j], acc[i][j], 0, 0, 0);
    }
    __syncthreads();
  }

#pragma unroll
  for (int i = 0; i < 4; i++) {
    const int row = m0 + 64 * wm + 16 * i + q * 4;
#pragma unroll
    for (int j = 0; j < 4; j++) {
      const int col = n0 + 64 * wn + 16 * j + c;
#pragma unroll
      for (int r = 0; r < 4; r++) {
        float v = acc[i][j][r] + bias0[col];
        v = v > 0.f ? v : 0.f;
        outbf[(size_t)(row + r) * ldo + col] = f2bf(v);
      }
    }
  }
}

// ---------------------------------------------------------------- GEMM2 fused
// A = H [NB][512] bf16; Bt = W2I [256][512] with s/t interleaved columns
// (col 2f = Ws[:,f], col 2f+1 = Wt[:,f]). Epilogue computes the coupling:
//   s = (tanh?)(C_even + bs[f]); t = C_odd + bt[f]; yb = xb*exp(s)+t
// writes yb to up to 2 fp32 + 2 bf16 destinations, accumulates jac.
__global__ __launch_bounds__(256, 4)
void gemm2_fused(const unsigned short* __restrict__ A, int lda,
                 const unsigned short* __restrict__ Bt, int ldb, int K,
                 const float* __restrict__ bs_l, const float* __restrict__ bt_l,
                 const float* __restrict__ XB, int ldxb,
                 float* __restrict__ d1, int ld1,
                 float* __restrict__ d2, int ld2,
                 unsigned short* __restrict__ e1, int lde1,
                 unsigned short* __restrict__ e2, int lde2,
                 float* __restrict__ jac, int do_tanh)
{
  __shared__ unsigned short As[128 * 64];
  __shared__ unsigned short Bs[128 * 64];
  const int tid = threadIdx.x;
  const int lane = tid & 63, wave = tid >> 6;
  const int wm = wave >> 1, wn = wave & 1;
  const int m0 = blockIdx.x * 128, n0 = blockIdx.y * 128;
  const int q = lane >> 4, c = lane & 15;

  const f32x4 z = {0.f, 0.f, 0.f, 0.f};
  f32x4 acc[4][4];
#pragma unroll
  for (int i = 0; i < 4; i++)
#pragma unroll
    for (int j = 0; j < 4; j++) acc[i][j] = z;

  for (int kt = 0; kt < K; kt += 64) {
#pragma unroll
    for (int i = 0; i < 4; i++) {
      const int cb = (wave * 4 + i) * 64;
      const int s = cb + lane;
      const int m = s >> 3;
      const int ko = ((s & 7) ^ (m & 7)) * 8;
      load_lds16(A  + (size_t)(m0 + m) * lda + kt + ko, As + cb * 8);
      load_lds16(Bt + (size_t)(n0 + m) * ldb + kt + ko, Bs + cb * 8);
    }
    __syncthreads();
#pragma unroll
    for (int ks = 0; ks < 2; ks++) {
      bf16x8 af[4], bfm[4];
#pragma unroll
      for (int i = 0; i < 4; i++) {
        const int ra = 64 * wm + 16 * i + c;
        const int rb = 64 * wn + 16 * i + c;
        af[i]  = *(const bf16x8*)(As + ra * 64 + ((ks * 4 + q) ^ (ra & 7)) * 8);
        bfm[i] = *(const bf16x8*)(Bs + rb * 64 + ((ks * 4 + q) ^ (rb & 7)) * 8);
      }
#pragma unroll
      for (int i = 0; i < 4; i++)
#pragma unroll
        for (int j = 0; j < 4; j++)
          acc[i][j] = __builtin_amdgcn_mfma_f32_16x16x32_bf16(af[i], bfm[j], acc[i][j], 0, 0, 0);
    }
    __syncthreads();
  }

  const int parity = c & 1;
  float jr[4][4];
#pragma unroll
  for (int i = 0; i < 4; i++)
#pragma unroll
    for (int r = 0; r < 4; r++) jr[i][r] = 0.f;

#pragma unroll
  for (int i = 0; i < 4; i++) {
#pragma unroll
    for (int j = 0; j < 4; j++) {
      const int col = n0 + 64 * wn + 16 * j + c;
#pragma unroll
      for (int r = 0; r < 4; r++) {
        const float val = acc[i][j][r];
        const float oth = __shfl_xor(val, 1);       // partner (t for even lanes)
        if (!parity) {
          const int feat = col >> 1;
          float s = val + bs_l[feat];
          if (do_tanh) s = fast_tanh(s);
          const float t = oth + bt_l[feat];
          const int row = m0 + 64 * wm + 16 * i + q * 4 + r;
          const float xb = XB[(size_t)row * ldxb + feat];
          const float yb = xb * __expf(s) + t;
          d1[(size_t)row * ld1 + feat] = yb;
          if (d2) d2[(size_t)row * ld2 + feat] = yb;
          const unsigned short ybb = f2bf(yb);
          e1[(size_t)row * lde1 + feat] = ybb;
          if (e2) e2[(size_t)row * lde2 + feat] = ybb;
          jr[i][r] += s;
        }
      }
    }
  }
  // jac: sum across even c-lanes (xor 2,4,8 keeps even<->even), add once
#pragma unroll
  for (int i = 0; i < 4; i++)
#pragma unroll
    for (int r = 0; r < 4; r++) {
      float v = jr[i][r];
      v += __shfl_xor(v, 2); v += __shfl_xor(v, 4); v += __shfl_xor(v, 8);
      if (c == 0) atomicAdd(&jac[m0 + 64 * wm + 16 * i + q * 4 + r], v);
    }
}

// ---------------------------------------------------------------- VQ argmax
// 1-D grid 1024: slice y = blockIdx.x & 15 (XCD-pinned: blockId%8 -> XCD, so
// each XCD touches 2 slices = 2 MB of P -> fits per-XCD L2), m-group = bx>>4.
// A (X rows) register-resident per wave (32 rows, full K=256 = 64 VGPRs);
// only P streams through LDS (64-code tiles, 32 KB, XOR-swizzled).
__global__ __launch_bounds__(256, 3)
void vq_argmax(const unsigned short* __restrict__ X,    // [NB][256] bf16
               const unsigned short* __restrict__ P,    // [NK][256] bf16
               const float* __restrict__ nbh,           // [NK] = 0.5*||p||^2
               unsigned long long* __restrict__ gbest)  // [NB] packed
{
  __shared__ unsigned short Bs[64 * 256];               // 32 KB
  const int tid = threadIdx.x;
  const int lane = tid & 63, wave = tid >> 6;
  const int y = blockIdx.x & 15;
  const int m0 = (blockIdx.x >> 4) * 128;
  const int q = lane >> 4, c = lane & 15;

  // A fragments: rows 32*wave + 16*i + c (i=0,1), k = kc*32 + q*8 .. +8
  bf16x8 af[2][8];
  {
    const unsigned short* x0 = X + (size_t)(m0 + 32 * wave + c) * 256 + q * 8;
    const unsigned short* x1 = x0 + (size_t)16 * 256;
#pragma unroll
    for (int kc = 0; kc < 8; kc++) {
      af[0][kc] = *(const bf16x8*)(x0 + kc * 32);
      af[1][kc] = *(const bf16x8*)(x1 + kc * 32);
    }
  }

  float bestv[8];
  int besti[8];
#pragma unroll
  for (int t = 0; t < 8; t++) { bestv[t] = -1e30f; besti[t] = 0; }

  for (int nt = 0; nt < 32; nt++) {
    const int n0 = y * 2048 + nt * 64;
    const unsigned short* pbase = P + (size_t)n0 * 256;
    // stage 64 codes x 512 B = 32 KB, XOR-swizzled within 8-chunk granules
#pragma unroll
    for (int u = 0; u < 8; u++) {
      const int chbase = u * 256 + wave * 64;   // wave-uniform LDS base
      const int ch = chbase + lane;
      const int row = ch >> 5, ccs = ch & 31;
      const int g = (ccs & 24) | ((ccs & 7) ^ (row & 7));
      load_lds16(pbase + (size_t)row * 256 + g * 8, Bs + (size_t)chbase * 8);
    }
    __syncthreads();

    const f32x4 z = {0.f, 0.f, 0.f, 0.f};
    f32x4 acc[2][4];
#pragma unroll
    for (int i = 0; i < 2; i++)
#pragma unroll
      for (int j = 0; j < 4; j++) acc[i][j] = z;

#pragma unroll
    for (int j = 0; j < 4; j++) {
      const int rb = 16 * j + c;
#pragma unroll
      for (int kc = 0; kc < 8; kc++) {
        const int g = kc * 4 + q;
        const int cc = (g & 24) | ((g & 7) ^ (rb & 7));
        const bf16x8 bf = *(const bf16x8*)(Bs + rb * 256 + cc * 8);
        acc[0][j] = __builtin_amdgcn_mfma_f32_16x16x32_bf16(af[0][kc], bf, acc[0][j], 0, 0, 0);
        acc[1][j] = __builtin_amdgcn_mfma_f32_16x16x32_bf16(af[1][kc], bf, acc[1][j], 0, 0, 0);
      }
    }
    __syncthreads();

    // score = x.p - 0.5||p||^2 ; lane-local running argmax
#pragma unroll
    for (int j = 0; j < 4; j++) {
      const int col = n0 + 16 * j + c;
      const float nb = nbh[col];
#pragma unroll
      for (int i = 0; i < 2; i++)
#pragma unroll
        for (int r = 0; r < 4; r++) {
          const float sc = acc[i][j][r] - nb;
          const int t = i * 4 + r;
          if (sc > bestv[t]) { bestv[t] = sc; besti[t] = col; }
        }
    }
  }

  // reduce across the 16 c-lanes per slot; rows owned uniquely per (wave,q)
#pragma unroll
  for (int t = 0; t < 8; t++) {
    float lv = bestv[t]; int li = besti[t];
#pragma unroll
    for (int mk = 8; mk >= 1; mk >>= 1) {
      const float ov = __shfl_xor(lv, mk);
      const int oi = __shfl_xor(li, mk);
      if (ov > lv || (ov == lv && oi < li)) { lv = ov; li = oi; }
    }
    if (c == 0) {
      const int i = t >> 2, r = t & 3;
      const int row = m0 + 32 * wave + 16 * i + q * 4 + r;
      atomicMax(&gbest[row], packsi(lv, li));
    }
  }
}

// ---------------------------------------------------------------- prep kernels
__global__ void prep_weights(const float* __restrict__ W1,
                             const float* __restrict__ Ws,
                             const float* __restrict__ Wt,
                             unsigned short* __restrict__ W1T,   // [L][512][128]
                             unsigned short* __restrict__ W2I)   // [L][256][512] s/t interleaved
{
  const int idx = blockIdx.x * 256 + threadIdx.x;
  if (idx < NLAY * NHID * NHALF) {            // 262144
    const int l = idx >> 16;
    const int n = (idx >> 7) & 511;
    const int k = idx & 127;
    W1T[idx] = f2bf(W1[((size_t)l * NHALF + k) * NHID + n]);
  } else {
    const int j = idx - NLAY * NHID * NHALF;  // 524288
    if (j < NLAY * NF * NHID) {
      const int l = j >> 17;
      const int n = (j >> 9) & 255;           // interleaved col: 2f -> s, 2f+1 -> t
      const int k = j & 511;
      const int f = n >> 1;
      const float v = (n & 1) ? Wt[((size_t)l * NHID + k) * NHALF + f]
                              : Ws[((size_t)l * NHID + k) * NHALF + f];
      W2I[j] = f2bf(v);
    }
  }
}

__global__ void prep_prior(const float* __restrict__ prior,
                           unsigned short* __restrict__ pbf,
                           float* __restrict__ nbh)
{
  const int k = blockIdx.x * 4 + (threadIdx.x >> 6);   // one wave per code
  const int lane = threadIdx.x & 63;
  const float4 v = *(const float4*)(prior + (size_t)k * NF + lane * 4);
  ushort4 o;
  o.x = f2bf(v.x); o.y = f2bf(v.y); o.z = f2bf(v.z); o.w = f2bf(v.w);
  *(ushort4*)(pbf + (size_t)k * NF + lane * 4) = o;
  float s = v.x * v.x + v.y * v.y + v.z * v.z + v.w * v.w;
#pragma unroll
  for (int mk = 32; mk >= 1; mk >>= 1) s += __shfl_xor(s, mk);
  if (lane == 0) nbh[k] = 0.5f * s;
}

__global__ void prep_x0(const float* __restrict__ in,
                        unsigned short* __restrict__ xabf,   // [NB][128] bf16
                        float* __restrict__ jac,
                        unsigned long long* __restrict__ gbest,
                        float* __restrict__ accum)
{
  const int idx = blockIdx.x * 256 + threadIdx.x;
  if (idx < NB * NHALF) {
    const int b = idx >> 7, j = idx & 127;
    xabf[idx] = f2bf(in[((size_t)b << 8) + j]);
  }
  if (idx < NB) { jac[idx] = 0.f; gbest[idx] = 0ull; }
  if (idx < 2) accum[idx] = 0.f;
}

// ---------------------------------------------------------------- VQ finalize
__global__ void vq_finalize(const float* __restrict__ X,      // d_out x, fp32
                            const float* __restrict__ prior,
                            const unsigned long long* __restrict__ gbest,
                            const float* __restrict__ jac,
                            float* __restrict__ accum)        // [0]=dist,[1]=jac
{
  const int wave = threadIdx.x >> 6, lane = threadIdx.x & 63;
  const int gw = blockIdx.x * 4 + wave;        // 1024 waves, 8 rows each
  float accd = 0.f, accj = 0.f;
  for (int r = 0; r < 8; r++) {
    const int row = gw * 8 + r;
    const unsigned int idx = ~(unsigned int)(gbest[row]);   // low 32 bits = ~idx
    const float* x = X + (size_t)row * NF;
    const float* p = prior + (size_t)idx * NF;
#pragma unroll
    for (int u = 0; u < 4; u++) {
      const int d = lane + u * 64;
      const float df = x[d] - p[d];
      accd += df * df;
    }
    if (lane == 0) accj += jac[row];
  }
#pragma unroll
  for (int mk = 32; mk >= 1; mk >>= 1) {
    accd += __shfl_xor(accd, mk);
    accj += __shfl_xor(accj, mk);
  }
  __shared__ float sd[4], sj[4];
  if (lane == 0) { sd[wave] = accd; sj[wave] = accj; }
  __syncthreads();
  if (threadIdx.x == 0) {
    atomicAdd(&accum[0], sd[0] + sd[1] + sd[2] + sd[3]);
    atomicAdd(&accum[1], sj[0] + sj[1] + sj[2] + sj[3]);
  }
}

__global__ void finalize_loss(const float* __restrict__ acc, float* __restrict__ loss) {
  if (threadIdx.x == 0 && blockIdx.x == 0)
    loss[0] = 1.25f * (0.5f * acc[0] / (float)NB) - acc[1] / (float)NB;
}

// ---------------------------------------------------------------- launch
extern "C" void kernel_launch(void* const* d_in, const int* in_sizes, int n_in,
                              void* d_out, int out_size, void* d_ws, size_t ws_size,
                              hipStream_t stream)
{
  (void)in_sizes; (void)n_in; (void)out_size; (void)ws_size;
  const float* inputs = (const float*)d_in[0];
  const float* W1 = (const float*)d_in[1];
  const float* b1 = (const float*)d_in[2];
  const float* Ws = (const float*)d_in[3];
  const float* bs = (const float*)d_in[4];
  const float* Wt = (const float*)d_in[5];
  const float* bt = (const float*)d_in[6];
  const float* prior = (const float*)d_in[7];

  char* p = (char*)d_ws;
  auto alloc = [&](size_t bytes) { char* r = p; p += (bytes + 255) & ~(size_t)255; return r; };
  unsigned short* W1T  = (unsigned short*)alloc((size_t)NLAY * NHID * NHALF * 2);
  unsigned short* W2I  = (unsigned short*)alloc((size_t)NLAY * NF * NHID * 2);
  unsigned short* PBF  = (unsigned short*)alloc((size_t)NK * NF * 2);
  float* NBH           = (float*)alloc((size_t)NK * 4);
  unsigned short* XABF = (unsigned short*)alloc((size_t)NB * NHALF * 2);
  unsigned short* HBF  = (unsigned short*)alloc((size_t)NB * NHID * 2);
  float* YB0           = (float*)alloc((size_t)NB * NHALF * 4);
  float* YB1           = (float*)alloc((size_t)NB * NHALF * 4);
  unsigned short* XFBF = (unsigned short*)alloc((size_t)NB * NF * 2);
  float* JAC           = (float*)alloc((size_t)NB * 4);
  unsigned long long* GBEST = (unsigned long long*)alloc((size_t)NB * 8);
  float* ACC           = (float*)alloc(256);

  float* xout = (float*)d_out;                 // [NB][NF]
  float* loss = xout + (size_t)NB * NF;        // scalar

  prep_weights<<<dim3((NLAY * NHID * NHALF + NLAY * NF * NHID) / 256), 256, 0, stream>>>(
      W1, Ws, Wt, W1T, W2I);
  prep_prior<<<dim3(NK / 4), 256, 0, stream>>>(prior, PBF, NBH);
  prep_x0<<<dim3(NB * NHALF / 256), 256, 0, stream>>>(inputs, XABF, JAC, GBEST, ACC);

  // recurrence: xb_0 = in[:,128:], xb_1 = in[:,:128], xb_2 = yb_0, xb_3 = yb_1
  // xout = [yb_3, yb_2]; XFBF = bf16(xout)
  struct Cfg {
    const float* xb; int ldxb;
    float* d1; int ld1; float* d2; int ld2;
    unsigned short* e1; int lde1; unsigned short* e2; int lde2;
    int tanh_;
  } cfg[NLAY] = {
    { inputs + NHALF, NF,  YB0, NHALF,        nullptr, 0,  XABF, NHALF, nullptr, 0, 1 },
    { inputs,         NF,  YB1, NHALF,        nullptr, 0,  XABF, NHALF, nullptr, 0, 1 },
    { YB0,         NHALF,  xout + NHALF, NF,  nullptr, 0,  XABF, NHALF, XFBF + NHALF, NF, 1 },
    { YB1,         NHALF,  xout, NF,          nullptr, 0,  XFBF, NF,    nullptr, 0, 0 },
  };

  for (int l = 0; l < NLAY; l++) {
    gemm1<<<dim3(NB / 128, NHID / 128), 256, 0, stream>>>(
        XABF, NHALF, W1T + (size_t)l * NHID * NHALF, NHALF, NHALF,
        b1 + l * NHID, HBF, NHID);
    gemm2_fused<<<dim3(NB / 128, NF / 128), 256, 0, stream>>>(
        HBF, NHID, W2I + (size_t)l * NF * NHID, NHID, NHID,
        bs + l * NHALF, bt + l * NHALF,
        cfg[l].xb, cfg[l].ldxb,
        cfg[l].d1, cfg[l].ld1, cfg[l].d2, cfg[l].ld2,
        cfg[l].e1, cfg[l].lde1, cfg[l].e2, cfg[l].lde2,
        JAC, cfg[l].tanh_);
  }

  vq_argmax<<<dim3(64 * 16), 256, 0, stream>>>(XFBF, PBF, NBH, GBEST);
  vq_finalize<<<dim3(256), 256, 0, stream>>>(xout, prior, GBEST, JAC, ACC);
  finalize_loss<<<1, 1, 0, stream>>>(ACC, loss);
}

// Round 4
// 347.992 us; speedup vs baseline: 2.0133x; 1.3358x over previous
//
#include <hip/hip_runtime.h>
#include <stdint.h>

// ---------------------------------------------------------------- constants
#define NB     8192     // batch
#define NF     256      // features
#define NHALF  128      // F/2
#define NHID   512      // hidden = 2F
#define NLAY   4        // coupling layers
#define NK     32768    // codebook size

typedef __attribute__((ext_vector_type(8))) short bf16x8;   // 8 bf16 = 4 VGPR
typedef __attribute__((ext_vector_type(4))) float f32x4;

static __device__ __forceinline__ unsigned short f2bf(float f) {
  union { float f; unsigned int u; } v; v.f = f;
  return (unsigned short)((v.u + 0x7FFFu + ((v.u >> 16) & 1u)) >> 16);  // RNE
}

// async global->LDS, 16B per lane; LDS dest = wave-uniform base + lane*16
static __device__ __forceinline__ void load_lds16(const void* g, void* l) {
  __builtin_amdgcn_global_load_lds(
      (const __attribute__((address_space(1))) unsigned int*)g,
      (__attribute__((address_space(3))) unsigned int*)l, 16, 0, 0);
}

// pack (score, idx) so u64 max == argmax with smallest-index tiebreak
static __device__ __forceinline__ unsigned long long packsi(float v, int idx) {
  unsigned int b = __float_as_uint(v);
  b = (b & 0x80000000u) ? ~b : (b | 0x80000000u);   // order-preserving map
  return ((unsigned long long)b << 32) | (unsigned int)(~(unsigned int)idx);
}

static __device__ __forceinline__ float fast_tanh(float x) {
  const float xc = fminf(fmaxf(x, -15.f), 15.f);
  const float e2 = __expf(2.f * xc);
  return 1.f - 2.f / (e2 + 1.f);
}

// ---------------------------------------------------------------- fused flow layer
// One block = 32 batch rows. Stage 1: h[32][512] = relu(xa@W1+b1) kept in LDS.
// Stage 2: C = h @ W2I (s/t col-interleaved) + coupling epilogue.
// All LDS tiles use the PROVEN layout: [kseg][row][64 shorts] (128 B row
// stride) with 3-bit XOR chunk swizzle -> 0 bank conflicts (R2 evidence).
__global__ __launch_bounds__(256, 1)
void flow_layer(const unsigned short* __restrict__ XA,      // [NB][128] bf16
                const unsigned short* __restrict__ W1Tl,    // [512][128] bf16
                const unsigned short* __restrict__ W2Il,    // [256][512] bf16 interleaved
                const float* __restrict__ b1l,              // [512]
                const float* __restrict__ bsl,              // [128]
                const float* __restrict__ btl,              // [128]
                const float* __restrict__ XB, int ldxb,
                float* __restrict__ d1, int ld1,
                float* __restrict__ d2, int ld2,
                unsigned short* __restrict__ e1, int lde1,
                unsigned short* __restrict__ e2, int lde2,
                float* __restrict__ jac, int do_tanh)
{
  __shared__ unsigned short Hs[8 * 32 * 64];    // 32 KB  h as [kseg8][row32][64]
  __shared__ unsigned short Bs[2 * 128 * 64];   // 32 KB  staging (stage1/stage2)
  const int tid = threadIdx.x;
  const int lane = tid & 63, wave = tid >> 6;
  const int q = lane >> 4, c = lane & 15;
  const int m0 = blockIdx.x * 32;

  // stage-1 A fragments straight from global (8 x 16B loads, L2-hot)
  bf16x8 af1[2][4];
#pragma unroll
  for (int i = 0; i < 2; i++) {
    const unsigned short* xr = XA + (size_t)(m0 + 16 * i + c) * 128 + q * 8;
#pragma unroll
    for (int kw = 0; kw < 4; kw++) af1[i][kw] = *(const bf16x8*)(xr + kw * 32);
  }

  // ---- stage 1: 4 chunks of 128 hidden cols, full K=128 per chunk
  for (int nc = 0; nc < 4; nc++) {
    if (nc) __syncthreads();
    // stage W1T[nc*128 .. +128][0..128] as [kseg2][128][64]; 2048 chunks
#pragma unroll
    for (int u = 0; u < 8; u++) {
      const int chb = (wave * 8 + u) * 64;
      const int ch = chb + lane;
      const int kseg = ch >> 10, cs = ch & 1023;
      const int row = cs >> 3, cc = (cs & 7) ^ (row & 7);
      load_lds16(W1Tl + (size_t)(nc * 128 + row) * 128 + kseg * 64 + cc * 8,
                 Bs + chb * 8);
    }
    __syncthreads();

    const f32x4 z = {0.f, 0.f, 0.f, 0.f};
    f32x4 acc1[2][2];
#pragma unroll
    for (int i = 0; i < 2; i++)
#pragma unroll
      for (int j = 0; j < 2; j++) acc1[i][j] = z;

#pragma unroll
    for (int kw = 0; kw < 4; kw++) {
      const int kseg = kw >> 1, g = (kw & 1) * 4 + q;
#pragma unroll
      for (int j = 0; j < 2; j++) {
        const int rb = wave * 32 + 16 * j + c;
        const bf16x8 bf = *(const bf16x8*)(Bs + (kseg * 128 + rb) * 64 + (g ^ (rb & 7)) * 8);
        acc1[0][j] = __builtin_amdgcn_mfma_f32_16x16x32_bf16(af1[0][kw], bf, acc1[0][j], 0, 0, 0);
        acc1[1][j] = __builtin_amdgcn_mfma_f32_16x16x32_bf16(af1[1][kw], bf, acc1[1][j], 0, 0, 0);
      }
    }

    // h epilogue -> Hs [kseg][row][64] swizzled
#pragma unroll
    for (int i = 0; i < 2; i++)
#pragma unroll
      for (int j = 0; j < 2; j++) {
        const int hcol = nc * 128 + wave * 32 + 16 * j + c;
        const float bb = b1l[hcol];
        const int kseg = hcol >> 6, kin = hcol & 63;
#pragma unroll
        for (int r = 0; r < 4; r++) {
          float v = acc1[i][j][r] + bb;
          v = v > 0.f ? v : 0.f;
          const int row = 16 * i + q * 4 + r;
          const int cc = ((kin >> 3) ^ (row & 7)) * 8 + (kin & 7);
          Hs[(kseg * 32 + row) * 64 + cc] = f2bf(v);
        }
      }
  }
  __syncthreads();

  // ---- stage 2: C[32][256] = h @ W2I, K=512 in 8 tiles of 64
  const f32x4 z = {0.f, 0.f, 0.f, 0.f};
  f32x4 acc2[2][4];
#pragma unroll
  for (int i = 0; i < 2; i++)
#pragma unroll
    for (int j = 0; j < 4; j++) acc2[i][j] = z;

  for (int kt = 0; kt < 8; kt++) {
    if (kt) __syncthreads();
    // stage W2I[0..256][kt*64 .. +64] as [256][64]; 2048 chunks
#pragma unroll
    for (int u = 0; u < 8; u++) {
      const int chb = (wave * 8 + u) * 64;
      const int ch = chb + lane;
      const int row = ch >> 3, cc = (ch & 7) ^ (row & 7);
      load_lds16(W2Il + (size_t)row * 512 + kt * 64 + cc * 8, Bs + chb * 8);
    }
    __syncthreads();

#pragma unroll
    for (int ks = 0; ks < 2; ks++) {
      const int g = ks * 4 + q;
      bf16x8 af[2];
#pragma unroll
      for (int i = 0; i < 2; i++) {
        const int ra = 16 * i + c;
        af[i] = *(const bf16x8*)(Hs + (kt * 32 + ra) * 64 + (g ^ (ra & 7)) * 8);
      }
#pragma unroll
      for (int j = 0; j < 4; j++) {
        const int rb = wave * 64 + 16 * j + c;
        const bf16x8 bf = *(const bf16x8*)(Bs + rb * 64 + (g ^ (rb & 7)) * 8);
        acc2[0][j] = __builtin_amdgcn_mfma_f32_16x16x32_bf16(af[0], bf, acc2[0][j], 0, 0, 0);
        acc2[1][j] = __builtin_amdgcn_mfma_f32_16x16x32_bf16(af[1], bf, acc2[1][j], 0, 0, 0);
      }
    }
  }

  // ---- coupling epilogue (cols s/t interleaved: even=s, odd=t)
  const int parity = c & 1;
  float jr[2][4];
#pragma unroll
  for (int i = 0; i < 2; i++)
#pragma unroll
    for (int r = 0; r < 4; r++) jr[i][r] = 0.f;

#pragma unroll
  for (int i = 0; i < 2; i++) {
#pragma unroll
    for (int j = 0; j < 4; j++) {
      const int col = wave * 64 + 16 * j + c;
#pragma unroll
      for (int r = 0; r < 4; r++) {
        const float val = acc2[i][j][r];
        const float oth = __shfl_xor(val, 1);
        if (!parity) {
          const int feat = col >> 1;
          float s = val + bsl[feat];
          if (do_tanh) s = fast_tanh(s);
          const float t = oth + btl[feat];
          const int row = m0 + 16 * i + q * 4 + r;
          const float xb = XB[(size_t)row * ldxb + feat];
          const float yb = xb * __expf(s) + t;
          d1[(size_t)row * ld1 + feat] = yb;
          if (d2) d2[(size_t)row * ld2 + feat] = yb;
          const unsigned short ybb = f2bf(yb);
          e1[(size_t)row * lde1 + feat] = ybb;
          if (e2) e2[(size_t)row * lde2 + feat] = ybb;
          jr[i][r] += s;
        }
      }
    }
  }
#pragma unroll
  for (int i = 0; i < 2; i++)
#pragma unroll
    for (int r = 0; r < 4; r++) {
      float v = jr[i][r];
      v += __shfl_xor(v, 2); v += __shfl_xor(v, 4); v += __shfl_xor(v, 8);
      if (c == 0) atomicAdd(&jac[m0 + 16 * i + q * 4 + r], v);
    }
}

// ---------------------------------------------------------------- VQ argmax
// Grid 512: slice = bx & 15 (XCD-pinned, 2 MB P per XCD -> L2-resident),
// m-group = bx >> 4 (256 rows). Each wave: 64 register-resident X rows
// (af[4][8] = 128 VGPR) -> 4 MFMA per B-read (LDS traffic halved vs R3).
// P tile [kseg4][code64][64] (128 B stride + XOR3: proven 0-conflict layout).
__global__ __launch_bounds__(256, 2)
void vq_argmax(const unsigned short* __restrict__ X,    // [NB][256] bf16
               const unsigned short* __restrict__ P,    // [NK][256] bf16
               const float* __restrict__ nbh,           // [NK] = 0.5*||p||^2
               unsigned long long* __restrict__ gbest)  // [NB] packed
{
  __shared__ unsigned short Bs[4 * 64 * 64];            // 32 KB
  const int tid = threadIdx.x;
  const int lane = tid & 63, wave = tid >> 6;
  const int y = blockIdx.x & 15;
  const int m0 = (blockIdx.x >> 4) * 256;
  const int q = lane >> 4, c = lane & 15;
  const int mw = m0 + wave * 64;

  bf16x8 af[4][8];
#pragma unroll
  for (int i = 0; i < 4; i++) {
    const unsigned short* xr = X + (size_t)(mw + 16 * i + c) * 256 + q * 8;
#pragma unroll
    for (int kc = 0; kc < 8; kc++) af[i][kc] = *(const bf16x8*)(xr + kc * 32);
  }

  float bestv[16];
  int besti[16];
#pragma unroll
  for (int t = 0; t < 16; t++) { bestv[t] = -1e30f; besti[t] = 0; }

  for (int nt = 0; nt < 32; nt++) {
    const int n0 = y * 2048 + nt * 64;
    if (nt) __syncthreads();
    // stage 64 codes x 256 k as [kseg4][64][64]; 2048 chunks, wave w = kseg w
#pragma unroll
    for (int u = 0; u < 8; u++) {
      const int chb = (wave * 8 + u) * 64;
      const int ch = chb + lane;
      const int kseg = ch >> 9, cs = ch & 511;
      const int row = cs >> 3, cc = (cs & 7) ^ (row & 7);
      load_lds16(P + (size_t)(n0 + row) * 256 + kseg * 64 + cc * 8, Bs + chb * 8);
    }
    __syncthreads();

    const f32x4 z = {0.f, 0.f, 0.f, 0.f};
    f32x4 acc[4][4];
#pragma unroll
    for (int i = 0; i < 4; i++)
#pragma unroll
      for (int j = 0; j < 4; j++) acc[i][j] = z;

#pragma unroll
    for (int kseg = 0; kseg < 4; kseg++)
#pragma unroll
      for (int ks = 0; ks < 2; ks++) {
        const int kc = kseg * 2 + ks;
        const int g = ks * 4 + q;
#pragma unroll
        for (int j = 0; j < 4; j++) {
          const int rb = 16 * j + c;
          const bf16x8 bf = *(const bf16x8*)(Bs + (kseg * 64 + rb) * 64 + (g ^ (rb & 7)) * 8);
          acc[0][j] = __builtin_amdgcn_mfma_f32_16x16x32_bf16(af[0][kc], bf, acc[0][j], 0, 0, 0);
          acc[1][j] = __builtin_amdgcn_mfma_f32_16x16x32_bf16(af[1][kc], bf, acc[1][j], 0, 0, 0);
          acc[2][j] = __builtin_amdgcn_mfma_f32_16x16x32_bf16(af[2][kc], bf, acc[2][j], 0, 0, 0);
          acc[3][j] = __builtin_amdgcn_mfma_f32_16x16x32_bf16(af[3][kc], bf, acc[3][j], 0, 0, 0);
        }
      }

    // lane-local running argmax (ascending col + strict > = first-index ties)
#pragma unroll
    for (int j = 0; j < 4; j++) {
      const int col = n0 + 16 * j + c;
      const float nb = nbh[col];
#pragma unroll
      for (int i = 0; i < 4; i++)
#pragma unroll
        for (int r = 0; r < 4; r++) {
          const float sc = acc[i][j][r] - nb;
          const int t = i * 4 + r;
          if (sc > bestv[t]) { bestv[t] = sc; besti[t] = col; }
        }
    }
  }

  // reduce across 16 c-lanes per slot; rows unique per (wave, i, q, r)
#pragma unroll
  for (int t = 0; t < 16; t++) {
    float lv = bestv[t]; int li = besti[t];
#pragma unroll
    for (int mk = 8; mk >= 1; mk >>= 1) {
      const float ov = __shfl_xor(lv, mk);
      const int oi = __shfl_xor(li, mk);
      if (ov > lv || (ov == lv && oi < li)) { lv = ov; li = oi; }
    }
    if (c == 0) {
      const int row = mw + 16 * (t >> 2) + q * 4 + (t & 3);
      atomicMax(&gbest[row], packsi(lv, li));
    }
  }
}

// ---------------------------------------------------------------- fused prep
// blocks [0,8192): prior (4 codes/block) | [8192,11264): weights | rest: x0
__global__ void prep_all(const float* __restrict__ W1,
                         const float* __restrict__ Ws,
                         const float* __restrict__ Wt,
                         const float* __restrict__ prior,
                         const float* __restrict__ in,
                         unsigned short* __restrict__ W1T,   // [L][512][128]
                         unsigned short* __restrict__ W2I,   // [L][256][512]
                         unsigned short* __restrict__ pbf,
                         float* __restrict__ nbh,
                         unsigned short* __restrict__ xabf,
                         float* __restrict__ jac,
                         unsigned long long* __restrict__ gbest,
                         float* __restrict__ accum)
{
  const int bx = blockIdx.x;
  if (bx < NK / 4) {
    const int k = bx * 4 + (threadIdx.x >> 6);
    const int lane = threadIdx.x & 63;
    const float4 v = *(const float4*)(prior + (size_t)k * NF + lane * 4);
    ushort4 o;
    o.x = f2bf(v.x); o.y = f2bf(v.y); o.z = f2bf(v.z); o.w = f2bf(v.w);
    *(ushort4*)(pbf + (size_t)k * NF + lane * 4) = o;
    float s = v.x * v.x + v.y * v.y + v.z * v.z + v.w * v.w;
#pragma unroll
    for (int mk = 32; mk >= 1; mk >>= 1) s += __shfl_xor(s, mk);
    if (lane == 0) nbh[k] = 0.5f * s;
  } else if (bx < NK / 4 + 3072) {
    const int idx = (bx - NK / 4) * 256 + threadIdx.x;
    if (idx < NLAY * NHID * NHALF) {            // 262144
      const int l = idx >> 16;
      const int n = (idx >> 7) & 511;
      const int k = idx & 127;
      W1T[idx] = f2bf(W1[((size_t)l * NHALF + k) * NHID + n]);
    } else {
      const int j = idx - NLAY * NHID * NHALF;  // < 524288
      const int l = j >> 17;
      const int n = (j >> 9) & 255;             // 2f -> s, 2f+1 -> t
      const int k = j & 511;
      const int f = n >> 1;
      const float v = (n & 1) ? Wt[((size_t)l * NHID + k) * NHALF + f]
                              : Ws[((size_t)l * NHID + k) * NHALF + f];
      W2I[j] = f2bf(v);
    }
  } else {
    const int idx = (bx - NK / 4 - 3072) * 256 + threadIdx.x;
    if (idx < NB * NHALF) {
      const int b = idx >> 7, j = idx & 127;
      xabf[idx] = f2bf(in[((size_t)b << 8) + j]);
    }
    if (idx < NB) { jac[idx] = 0.f; gbest[idx] = 0ull; }
    if (idx < 2) accum[idx] = 0.f;
  }
}

// ---------------------------------------------------------------- VQ finalize
__global__ void vq_finalize(const float* __restrict__ X,      // d_out x, fp32
                            const float* __restrict__ prior,
                            const unsigned long long* __restrict__ gbest,
                            const float* __restrict__ jac,
                            float* __restrict__ accum)        // [0]=dist,[1]=jac
{
  const int wave = threadIdx.x >> 6, lane = threadIdx.x & 63;
  const int gw = blockIdx.x * 4 + wave;        // 1024 waves, 8 rows each
  float accd = 0.f, accj = 0.f;
  for (int r = 0; r < 8; r++) {
    const int row = gw * 8 + r;
    const unsigned int idx = ~(unsigned int)(gbest[row]);   // low 32 bits = ~idx
    const float* x = X + (size_t)row * NF;
    const float* p = prior + (size_t)idx * NF;
#pragma unroll
    for (int u = 0; u < 4; u++) {
      const int d = lane + u * 64;
      const float df = x[d] - p[d];
      accd += df * df;
    }
    if (lane == 0) accj += jac[row];
  }
#pragma unroll
  for (int mk = 32; mk >= 1; mk >>= 1) {
    accd += __shfl_xor(accd, mk);
    accj += __shfl_xor(accj, mk);
  }
  __shared__ float sd[4], sj[4];
  if (lane == 0) { sd[wave] = accd; sj[wave] = accj; }
  __syncthreads();
  if (threadIdx.x == 0) {
    atomicAdd(&accum[0], sd[0] + sd[1] + sd[2] + sd[3]);
    atomicAdd(&accum[1], sj[0] + sj[1] + sj[2] + sj[3]);
  }
}

__global__ void finalize_loss(const float* __restrict__ acc, float* __restrict__ loss) {
  if (threadIdx.x == 0 && blockIdx.x == 0)
    loss[0] = 1.25f * (0.5f * acc[0] / (float)NB) - acc[1] / (float)NB;
}

// ---------------------------------------------------------------- launch
extern "C" void kernel_launch(void* const* d_in, const int* in_sizes, int n_in,
                              void* d_out, int out_size, void* d_ws, size_t ws_size,
                              hipStream_t stream)
{
  (void)in_sizes; (void)n_in; (void)out_size; (void)ws_size;
  const float* inputs = (const float*)d_in[0];
  const float* W1 = (const float*)d_in[1];
  const float* b1 = (const float*)d_in[2];
  const float* Ws = (const float*)d_in[3];
  const float* bs = (const float*)d_in[4];
  const float* Wt = (const float*)d_in[5];
  const float* bt = (const float*)d_in[6];
  const float* prior = (const float*)d_in[7];

  char* p = (char*)d_ws;
  auto alloc = [&](size_t bytes) { char* r = p; p += (bytes + 255) & ~(size_t)255; return r; };
  unsigned short* W1T  = (unsigned short*)alloc((size_t)NLAY * NHID * NHALF * 2);
  unsigned short* W2I  = (unsigned short*)alloc((size_t)NLAY * NF * NHID * 2);
  unsigned short* PBF  = (unsigned short*)alloc((size_t)NK * NF * 2);
  float* NBH           = (float*)alloc((size_t)NK * 4);
  unsigned short* XABF = (unsigned short*)alloc((size_t)NB * NHALF * 2);
  float* YB0           = (float*)alloc((size_t)NB * NHALF * 4);
  float* YB1           = (float*)alloc((size_t)NB * NHALF * 4);
  unsigned short* XFBF = (unsigned short*)alloc((size_t)NB * NF * 2);
  float* JAC           = (float*)alloc((size_t)NB * 4);
  unsigned long long* GBEST = (unsigned long long*)alloc((size_t)NB * 8);
  float* ACC           = (float*)alloc(256);

  float* xout = (float*)d_out;                 // [NB][NF]
  float* loss = xout + (size_t)NB * NF;        // scalar

  prep_all<<<dim3(NK / 4 + 3072 + 4096), 256, 0, stream>>>(
      W1, Ws, Wt, prior, inputs, W1T, W2I, PBF, NBH, XABF, JAC, GBEST, ACC);

  // recurrence: xb_0 = in[:,128:], xb_1 = in[:,:128], xb_2 = yb_0, xb_3 = yb_1
  // xout = [yb_3, yb_2]; XFBF = bf16(xout)
  struct Cfg {
    const float* xb; int ldxb;
    float* d1; int ld1; float* d2; int ld2;
    unsigned short* e1; int lde1; unsigned short* e2; int lde2;
    int tanh_;
  } cfg[NLAY] = {
    { inputs + NHALF, NF,  YB0, NHALF,        nullptr, 0,  XABF, NHALF, nullptr, 0, 1 },
    { inputs,         NF,  YB1, NHALF,        nullptr, 0,  XABF, NHALF, nullptr, 0, 1 },
    { YB0,         NHALF,  xout + NHALF, NF,  nullptr, 0,  XABF, NHALF, XFBF + NHALF, NF, 1 },
    { YB1,         NHALF,  xout, NF,          nullptr, 0,  XFBF, NF,    nullptr, 0, 0 },
  };

  for (int l = 0; l < NLAY; l++) {
    flow_layer<<<dim3(NB / 32), 256, 0, stream>>>(
        XABF, W1T + (size_t)l * NHID * NHALF, W2I + (size_t)l * NF * NHID,
        b1 + l * NHID, bs + l * NHALF, bt + l * NHALF,
        cfg[l].xb, cfg[l].ldxb,
        cfg[l].d1, cfg[l].ld1, cfg[l].d2, cfg[l].ld2,
        cfg[l].e1, cfg[l].lde1, cfg[l].e2, cfg[l].lde2,
        JAC, cfg[l].tanh_);
  }

  vq_argmax<<<dim3(32 * 16), 256, 0, stream>>>(XFBF, PBF, NBH, GBEST);
  vq_finalize<<<dim3(256), 256, 0, stream>>>(xout, prior, GBEST, JAC, ACC);
  finalize_loss<<<1, 1, 0, stream>>>(ACC, loss);
}